// Round 14
// baseline (55.324 us; speedup 1.0000x reference)
//
#include <hip/hip_runtime.h>
#include <hip/hip_bf16.h>

#define CIN   64
#define COUT  128
#define TT    256
#define VV    25
#define TV    (TT * VV)   // 6400
#define KW    9
#define PAD   4
#define YROW  28          // padded bf16 y row: 56B
#define YSTR  (TT * YROW) // 7168 shorts per (n,c) plane

typedef __attribute__((ext_vector_type(8))) short short8;   // 8 bf16 (4 VGPRs)
typedef __attribute__((ext_vector_type(4))) float f32x4;

__device__ __forceinline__ unsigned f2b(float f) {          // fp32 -> bf16 bits (RNE)
    unsigned u = __builtin_bit_cast(unsigned, f);
    return (u + 0x7FFFu + ((u >> 16) & 1u)) >> 16;
}
__device__ __forceinline__ float lof(unsigned u) {          // low bf16 -> f32
    return __builtin_bit_cast(float, u << 16);
}
__device__ __forceinline__ float hif(unsigned u) {          // high bf16 -> f32
    return __builtin_bit_cast(float, u & 0xffff0000u);
}
// conv LDS tile swizzle: [row][128B], XOR slot with (row&7)
__device__ __forceinline__ int swz(int row, int cbyte) {
    return row * 128 + ((cbyte & ~15) ^ ((row & 7) << 4)) + (cbyte & 15);
}

// ---------------- Kernel A: 1x1 conv + BN via bf16 MFMA (unchanged) ----------------
__global__ __launch_bounds__(256) void conv_mfma(
    const float* __restrict__ x, const float* __restrict__ w,
    const float* __restrict__ cb, const float* __restrict__ gamma,
    const float* __restrict__ beta, const float* __restrict__ rm,
    const float* __restrict__ rv, unsigned short* __restrict__ y)
{
    __shared__ __align__(16) unsigned short Wl[COUT * 64];   // 16 KB, swizzled
    __shared__ __align__(16) unsigned short Xl[128 * 64];    // 16 KB, swizzled [pos][c]
    __shared__ float sc[COUT];
    __shared__ float of[COUT];

    const int pc  = blockIdx.x;       // 0..49
    const int n   = blockIdx.y;       // 0..15
    const int tid = threadIdx.x;
    const int posbase = pc * 128;

    if (tid < COUT) {
        const float s = gamma[tid] * rsqrtf(rv[tid] + 1e-5f);
        sc[tid] = s;
        of[tid] = cb[tid] * s + beta[tid] - rm[tid] * s;
    }
    for (int idx = tid; idx < 2048; idx += 256) {
        const int c4 = idx & 15, o = idx >> 4;
        const f32x4 wv = *(const f32x4*)(w + o * 64 + c4 * 4);
        uint2 pk;
        pk.x = f2b(wv.x) | (f2b(wv.y) << 16);
        pk.y = f2b(wv.z) | (f2b(wv.w) << 16);
        *(uint2*)((char*)Wl + swz(o, c4 * 8)) = pk;
    }
    for (int idx = tid; idx < 2048; idx += 256) {
        const int pos = idx & 127, c4 = idx >> 7;
        const float* xp = x + (size_t)n * CIN * TV + (size_t)(c4 * 4) * TV + posbase + pos;
        const float a0 = xp[0], a1 = xp[TV], a2 = xp[2 * TV], a3 = xp[3 * TV];
        uint2 pk;
        pk.x = f2b(a0) | (f2b(a1) << 16);
        pk.y = f2b(a2) | (f2b(a3) << 16);
        *(uint2*)((char*)Xl + swz(pos, c4 * 8)) = pk;
    }
    __syncthreads();

    const int wv_ = tid >> 6, lane = tid & 63;
    const int lr = lane & 15, lh = lane >> 4;   // lh in 0..3

    short8 afr[2][2];
#pragma unroll
    for (int m0 = 0; m0 < 2; ++m0)
#pragma unroll
        for (int kh = 0; kh < 2; ++kh)
            afr[m0][kh] = *(const short8*)((const char*)Wl +
                              swz(wv_ * 32 + m0 * 16 + lr, kh * 64 + lh * 16));

    f32x4 acc[2][8];
#pragma unroll
    for (int m0 = 0; m0 < 2; ++m0)
#pragma unroll
        for (int n0 = 0; n0 < 8; ++n0) acc[m0][n0] = (f32x4){0.f, 0.f, 0.f, 0.f};

#pragma unroll
    for (int n0 = 0; n0 < 8; ++n0) {
        const int prow = n0 * 16 + lr;
        const short8 b0 = *(const short8*)((const char*)Xl + swz(prow, lh * 16));
        const short8 b1 = *(const short8*)((const char*)Xl + swz(prow, 64 + lh * 16));
#pragma unroll
        for (int m0 = 0; m0 < 2; ++m0) {
            acc[m0][n0] = __builtin_amdgcn_mfma_f32_16x16x32_bf16(afr[m0][0], b0, acc[m0][n0], 0, 0, 0);
            acc[m0][n0] = __builtin_amdgcn_mfma_f32_16x16x32_bf16(afr[m0][1], b1, acc[m0][n0], 0, 0, 0);
        }
    }

    float scv[2][4], ofv[2][4];
#pragma unroll
    for (int m0 = 0; m0 < 2; ++m0)
#pragma unroll
        for (int r = 0; r < 4; ++r) {
            const int o = wv_ * 32 + m0 * 16 + lh * 4 + r;
            scv[m0][r] = sc[o];
            ofv[m0][r] = of[o];
        }

    const size_t ybase = (size_t)(n * COUT) * YSTR;
#pragma unroll
    for (int m0 = 0; m0 < 2; ++m0)
#pragma unroll
        for (int n0 = 0; n0 < 8; ++n0)
#pragma unroll
            for (int r = 0; r < 4; ++r) {
                const int o = wv_ * 32 + m0 * 16 + lh * 4 + r;
                const int pos = posbase + n0 * 16 + lr;
                const int t = pos / 25;
                const int v = pos - t * 25;
                const float val = acc[m0][n0][r] * scv[m0][r] + ofv[m0][r];
                y[ybase + (size_t)o * YSTR + t * YROW + v] = (unsigned short)f2b(val);
            }
}

// ---------------- Kernel B: temporal-window attention (v-split pairs) ----------------
// 2048 blocks x 512 threads. Thread pair (2t, 2t+1) owns halves of row t:
// h=0 -> v0..11, h=1 -> v12..24 (slot 12 masked to 0 for h=0; no divergence).
// Per-thread live state ~45 floats (vs 150 in the 1-t/thread version) ->
// ~5 waves/SIMD; dots are 13-FMA partials + one __shfl_xor(pd,1) combine.
// LDS reads/row: 3x b64 + 1 broadcast b32, uniform bank floor (14m mod 32
// sweeps 16 distinct evens; pair offset +6 keeps it uniform).
// Single pass, no-max online softmax (|s| <= ~40 << 88), row read once.
#define LOADHALF(rl, dst)                                                   \
    {                                                                       \
        const int b2_ = (rl) * 7 + h3;                                      \
        const uint2 a_ = tl2[b2_], b_ = tl2[b2_ + 1], c_ = tl2[b2_ + 2];    \
        const unsigned d_ = tlu[14 * (rl) + 12];                            \
        (dst)[0]  = lof(a_.x); (dst)[1]  = hif(a_.x);                       \
        (dst)[2]  = lof(a_.y); (dst)[3]  = hif(a_.y);                       \
        (dst)[4]  = lof(b_.x); (dst)[5]  = hif(b_.x);                       \
        (dst)[6]  = lof(b_.y); (dst)[7]  = hif(b_.y);                       \
        (dst)[8]  = lof(c_.x); (dst)[9]  = hif(c_.x);                       \
        (dst)[10] = lof(c_.y); (dst)[11] = hif(c_.y);                       \
        (dst)[12] = lof(d_) * hmask;                                        \
    }

__global__ __launch_bounds__(512) void attn_kernel(
    const unsigned short* __restrict__ y, const float* __restrict__ att0,
    float* __restrict__ out)
{
    __shared__ __align__(16) float sm[TV];   // 25.6 KB: bf16 tile (14.8KB), then fp32 overlay
    __shared__ float a0s[KW];

    uint4* tl4 = (uint4*)sm;                  // tile: 924 uint4 = 14784 B
    const uint2* tl2 = (const uint2*)sm;
    const unsigned* tlu = (const unsigned*)sm;

    const int nc  = blockIdx.x;       // n*COUT + c
    const int c   = nc & (COUT - 1);
    const int tid = threadIdx.x;

    if (tid < KW) a0s[tid] = att0[c * KW + tid];

    // zero halo: front uint4 [0,14) (rows -4..-1), back [910,924) (rows 256..259)
    if (tid < 28) {
        const int i = (tid < 14) ? tid : (896 + tid);
        tl4[i] = make_uint4(0, 0, 0, 0);
    }
    // stage: linear copy, 896 uint4, fully coalesced
    const uint4* yg = (const uint4*)(y + (size_t)nc * YSTR);
    {
        tl4[14 + tid] = yg[tid];
        const int ci = tid + 512;
        if (ci < 896) tl4[14 + ci] = yg[ci];
    }
    __syncthreads();

    const int t  = tid >> 1;          // local center row = t + 4
    const int h  = tid & 1;           // v-half: 0 -> v0..11, 1 -> v12..24
    const int h3 = h * 3;             // uint2 offset of own half within a row
    const float hmask = (float)h;

    float q[13];
    LOADHALF(t + 4, q);

    float osm[13], oa0[13];
    float den;
    {   // j = 4: self term (row == q, no LDS read)
        float pd = 0.f;
#pragma unroll
        for (int k = 0; k < 13; ++k) pd = fmaf(q[k], q[k], pd);
        const float full = pd + __shfl_xor(pd, 1);
        const float e = __expf(full * (1.f / 25.f));
        den = e;
        const float a = a0s[4];
#pragma unroll
        for (int k = 0; k < 13; ++k) { osm[k] = e * q[k]; oa0[k] = a * q[k]; }
    }

#pragma unroll
    for (int j = 0; j < KW; ++j) {
        if (j == 4) continue;
        float row[13];
        LOADHALF(t + j, row);
        float pd = 0.f;
#pragma unroll
        for (int k = 0; k < 13; ++k) pd = fmaf(row[k], q[k], pd);
        const float full = pd + __shfl_xor(pd, 1);
        const float e = __expf(full * (1.f / 25.f));
        den += e;
        const float a = a0s[j];
#pragma unroll
        for (int k = 0; k < 13; ++k) {
            osm[k] = fmaf(e, row[k], osm[k]);
            oa0[k] = fmaf(a, row[k], oa0[k]);
        }
    }

    const float inv = 1.f / den;

    // ---- overlay pack: h=0 -> out[t][0..11], h=1 -> out[t][12..24] ----
    __syncthreads();
    {
        float* dst = &sm[t * 25 + h * 12];
#pragma unroll
        for (int k = 0; k < 12; ++k) dst[k] = fmaf(osm[k], inv, oa0[k]);
        if (h) dst[12] = fmaf(osm[12], inv, oa0[12]);
    }
    __syncthreads();

    // ---- block-contiguous float4 stores: full 64B lines per instruction ----
    {
        float4* og = (float4*)(out + (size_t)nc * TV);
        const float4* sm4 = (const float4*)sm;
#pragma unroll
        for (int i = 0; i < 4; ++i) {
            const int ci = tid + i * 512;
            if (ci < TV / 4) og[ci] = sm4[ci];
        }
    }
}

extern "C" void kernel_launch(void* const* d_in, const int* in_sizes, int n_in,
                              void* d_out, int out_size, void* d_ws, size_t ws_size,
                              hipStream_t stream)
{
    const float* x     = (const float*)d_in[0];
    const float* w     = (const float*)d_in[1];
    const float* cb    = (const float*)d_in[2];
    const float* gamma = (const float*)d_in[3];
    const float* beta  = (const float*)d_in[4];
    const float* rm    = (const float*)d_in[5];
    const float* rv    = (const float*)d_in[6];
    const float* att0  = (const float*)d_in[7];
    float* out = (float*)d_out;
    unsigned short* y = (unsigned short*)d_ws;   // 2048*7168*2 = 29.4 MB padded bf16

    dim3 gA(TV / 128, 16);   // 50 x 16
    conv_mfma<<<gA, 256, 0, stream>>>(x, w, cb, gamma, beta, rm, rv, y);

    dim3 gB(16 * COUT);
    attn_kernel<<<gB, 512, 0, stream>>>(y, att0, out);
}

// Round 15
// 54.014 us; speedup vs baseline: 1.0243x; 1.0243x over previous
//
#include <hip/hip_runtime.h>
#include <hip/hip_bf16.h>

#define CIN   64
#define COUT  128
#define TT    256
#define VV    25
#define TV    (TT * VV)   // 6400
#define KW    9
#define PAD   4
#define YROW  28          // padded bf16 y row: 56B
#define YSTR  (TT * YROW) // 7168 shorts per (n,c) plane

typedef __attribute__((ext_vector_type(8))) short short8;   // 8 bf16 (4 VGPRs)
typedef __attribute__((ext_vector_type(4))) float f32x4;

__device__ __forceinline__ unsigned f2b(float f) {          // fp32 -> bf16 bits (RNE)
    unsigned u = __builtin_bit_cast(unsigned, f);
    return (u + 0x7FFFu + ((u >> 16) & 1u)) >> 16;
}
__device__ __forceinline__ float lof(unsigned u) {          // low bf16 -> f32
    return __builtin_bit_cast(float, u << 16);
}
__device__ __forceinline__ float hif(unsigned u) {          // high bf16 -> f32
    return __builtin_bit_cast(float, u & 0xffff0000u);
}
// conv LDS tile swizzle: [row][128B], XOR slot with (row&7)
__device__ __forceinline__ int swz(int row, int cbyte) {
    return row * 128 + ((cbyte & ~15) ^ ((row & 7) << 4)) + (cbyte & 15);
}

// ---------------- Kernel A: 1x1 conv + BN via bf16 MFMA (unchanged) ----------------
__global__ __launch_bounds__(256) void conv_mfma(
    const float* __restrict__ x, const float* __restrict__ w,
    const float* __restrict__ cb, const float* __restrict__ gamma,
    const float* __restrict__ beta, const float* __restrict__ rm,
    const float* __restrict__ rv, unsigned short* __restrict__ y)
{
    __shared__ __align__(16) unsigned short Wl[COUT * 64];   // 16 KB, swizzled
    __shared__ __align__(16) unsigned short Xl[128 * 64];    // 16 KB, swizzled [pos][c]
    __shared__ float sc[COUT];
    __shared__ float of[COUT];

    const int pc  = blockIdx.x;       // 0..49
    const int n   = blockIdx.y;       // 0..15
    const int tid = threadIdx.x;
    const int posbase = pc * 128;

    if (tid < COUT) {
        const float s = gamma[tid] * rsqrtf(rv[tid] + 1e-5f);
        sc[tid] = s;
        of[tid] = cb[tid] * s + beta[tid] - rm[tid] * s;
    }
    for (int idx = tid; idx < 2048; idx += 256) {
        const int c4 = idx & 15, o = idx >> 4;
        const f32x4 wv = *(const f32x4*)(w + o * 64 + c4 * 4);
        uint2 pk;
        pk.x = f2b(wv.x) | (f2b(wv.y) << 16);
        pk.y = f2b(wv.z) | (f2b(wv.w) << 16);
        *(uint2*)((char*)Wl + swz(o, c4 * 8)) = pk;
    }
    for (int idx = tid; idx < 2048; idx += 256) {
        const int pos = idx & 127, c4 = idx >> 7;
        const float* xp = x + (size_t)n * CIN * TV + (size_t)(c4 * 4) * TV + posbase + pos;
        const float a0 = xp[0], a1 = xp[TV], a2 = xp[2 * TV], a3 = xp[3 * TV];
        uint2 pk;
        pk.x = f2b(a0) | (f2b(a1) << 16);
        pk.y = f2b(a2) | (f2b(a3) << 16);
        *(uint2*)((char*)Xl + swz(pos, c4 * 8)) = pk;
    }
    __syncthreads();

    const int wv_ = tid >> 6, lane = tid & 63;
    const int lr = lane & 15, lh = lane >> 4;   // lh in 0..3

    short8 afr[2][2];
#pragma unroll
    for (int m0 = 0; m0 < 2; ++m0)
#pragma unroll
        for (int kh = 0; kh < 2; ++kh)
            afr[m0][kh] = *(const short8*)((const char*)Wl +
                              swz(wv_ * 32 + m0 * 16 + lr, kh * 64 + lh * 16));

    f32x4 acc[2][8];
#pragma unroll
    for (int m0 = 0; m0 < 2; ++m0)
#pragma unroll
        for (int n0 = 0; n0 < 8; ++n0) acc[m0][n0] = (f32x4){0.f, 0.f, 0.f, 0.f};

#pragma unroll
    for (int n0 = 0; n0 < 8; ++n0) {
        const int prow = n0 * 16 + lr;
        const short8 b0 = *(const short8*)((const char*)Xl + swz(prow, lh * 16));
        const short8 b1 = *(const short8*)((const char*)Xl + swz(prow, 64 + lh * 16));
#pragma unroll
        for (int m0 = 0; m0 < 2; ++m0) {
            acc[m0][n0] = __builtin_amdgcn_mfma_f32_16x16x32_bf16(afr[m0][0], b0, acc[m0][n0], 0, 0, 0);
            acc[m0][n0] = __builtin_amdgcn_mfma_f32_16x16x32_bf16(afr[m0][1], b1, acc[m0][n0], 0, 0, 0);
        }
    }

    float scv[2][4], ofv[2][4];
#pragma unroll
    for (int m0 = 0; m0 < 2; ++m0)
#pragma unroll
        for (int r = 0; r < 4; ++r) {
            const int o = wv_ * 32 + m0 * 16 + lh * 4 + r;
            scv[m0][r] = sc[o];
            ofv[m0][r] = of[o];
        }

    const size_t ybase = (size_t)(n * COUT) * YSTR;
#pragma unroll
    for (int m0 = 0; m0 < 2; ++m0)
#pragma unroll
        for (int n0 = 0; n0 < 8; ++n0)
#pragma unroll
            for (int r = 0; r < 4; ++r) {
                const int o = wv_ * 32 + m0 * 16 + lh * 4 + r;
                const int pos = posbase + n0 * 16 + lr;
                const int t = pos / 25;
                const int v = pos - t * 25;
                const float val = acc[m0][n0][r] * scv[m0][r] + ofv[m0][r];
                y[ybase + (size_t)o * YSTR + t * YROW + v] = (unsigned short)f2b(val);
            }
}

// ---------------- Kernel B: temporal-window attention (global-read, pipelined) ----------------
// 2048 blocks x 256 threads, t = tid. NO LDS staging: the 14.3 KB y-plane is
// L1/L2-resident after conv; rows are read directly from global with a 1-deep
// software pipeline (fetch row j+1 while processing row j; double-buffered
// named regs -> WAR deps stop the compiler hoisting all 63 loads).
// OOB rows: address clamped, payload masked to 0 (reference zero-pads: the
// zero row contributes exp(0)=1 to den and 0 to the sums).
// Single pass, no-max online softmax (|s| <= ~40 << 88), row read once.
// LDS = fp32 output overlay only (full-line stores; R4 lesson).

// fetch row (t+j-4) packed into buffer slot b: 6x uint2 + 1 dword + mask
#define FETCH(j, b)                                                         \
    {                                                                       \
        const int r_  = t + (j) - PAD;                                      \
        const int rc_ = min(max(r_, 0), TT - 1);                            \
        const uint2* rp_ = (const uint2*)(yp + rc_ * YROW);                 \
        pb0[b] = rp_[0]; pb1[b] = rp_[1]; pb2[b] = rp_[2];                  \
        pb3[b] = rp_[3]; pb4[b] = rp_[4]; pb5[b] = rp_[5];                  \
        pb6[b] = ((const unsigned*)rp_)[12];                                \
        okm[b] = ((unsigned)r_ < (unsigned)TT) ? 0xffffffffu : 0u;          \
    }

#define UNPACK(b, dst)                                                      \
    {                                                                       \
        const unsigned m_ = okm[b];                                         \
        const unsigned w0_ = pb0[b].x & m_, w1_ = pb0[b].y & m_;            \
        const unsigned w2_ = pb1[b].x & m_, w3_ = pb1[b].y & m_;            \
        const unsigned w4_ = pb2[b].x & m_, w5_ = pb2[b].y & m_;            \
        const unsigned w6_ = pb3[b].x & m_, w7_ = pb3[b].y & m_;            \
        const unsigned w8_ = pb4[b].x & m_, w9_ = pb4[b].y & m_;            \
        const unsigned wa_ = pb5[b].x & m_, wb_ = pb5[b].y & m_;            \
        const unsigned wc_ = pb6[b] & m_;                                   \
        (dst)[0]  = lof(w0_); (dst)[1]  = hif(w0_);                         \
        (dst)[2]  = lof(w1_); (dst)[3]  = hif(w1_);                         \
        (dst)[4]  = lof(w2_); (dst)[5]  = hif(w2_);                         \
        (dst)[6]  = lof(w3_); (dst)[7]  = hif(w3_);                         \
        (dst)[8]  = lof(w4_); (dst)[9]  = hif(w4_);                         \
        (dst)[10] = lof(w5_); (dst)[11] = hif(w5_);                         \
        (dst)[12] = lof(w6_); (dst)[13] = hif(w6_);                         \
        (dst)[14] = lof(w7_); (dst)[15] = hif(w7_);                         \
        (dst)[16] = lof(w8_); (dst)[17] = hif(w8_);                         \
        (dst)[18] = lof(w9_); (dst)[19] = hif(w9_);                         \
        (dst)[20] = lof(wa_); (dst)[21] = hif(wa_);                         \
        (dst)[22] = lof(wb_); (dst)[23] = hif(wb_);                         \
        (dst)[24] = lof(wc_);                                               \
    }

__global__ __launch_bounds__(256) void attn_kernel(
    const unsigned short* __restrict__ y, const float* __restrict__ att0,
    float* __restrict__ out)
{
    __shared__ __align__(16) float sm[TV];   // 25.6 KB fp32 output overlay

    const int nc  = blockIdx.x;       // n*COUT + c
    const int c   = nc & (COUT - 1);
    const int tid = threadIdx.x;
    const int t   = tid;

    const unsigned short* yp = y + (size_t)nc * YSTR;

    // att0 row: wave-uniform -> scalar loads, no LDS, no sync
    float a0v[KW];
#pragma unroll
    for (int j = 0; j < KW; ++j) a0v[j] = att0[c * KW + j];

    // q = own row t (always in range): fetch + unpack first
    float q[25];
    {
        const uint2* rp = (const uint2*)(yp + t * YROW);
        const uint2 a = rp[0], b = rp[1], cc = rp[2], d = rp[3], e = rp[4], f = rp[5];
        const unsigned g = ((const unsigned*)rp)[12];
        q[0]  = lof(a.x);  q[1]  = hif(a.x);  q[2]  = lof(a.y);  q[3]  = hif(a.y);
        q[4]  = lof(b.x);  q[5]  = hif(b.x);  q[6]  = lof(b.y);  q[7]  = hif(b.y);
        q[8]  = lof(cc.x); q[9]  = hif(cc.x); q[10] = lof(cc.y); q[11] = hif(cc.y);
        q[12] = lof(d.x);  q[13] = hif(d.x);  q[14] = lof(d.y);  q[15] = hif(d.y);
        q[16] = lof(e.x);  q[17] = hif(e.x);  q[18] = lof(e.y);  q[19] = hif(e.y);
        q[20] = lof(f.x);  q[21] = hif(f.x);  q[22] = lof(f.y);  q[23] = hif(f.y);
        q[24] = lof(g);
    }

    // double-buffered packed row regs (static indices after full unroll)
    uint2 pb0[2], pb1[2], pb2[2], pb3[2], pb4[2], pb5[2];
    unsigned pb6[2], okm[2];

    float osm[25], oa0[25];
#pragma unroll
    for (int v = 0; v < 25; ++v) { osm[v] = 0.f; oa0[v] = 0.f; }
    float den = 0.f;

    FETCH(0, 0);
#pragma unroll
    for (int j = 0; j < KW; ++j) {
        if (j + 1 < KW) FETCH(j + 1, (j + 1) & 1);
        float row[25];
        UNPACK(j & 1, row);
        float d0 = 0.f, d1 = 0.f;
#pragma unroll
        for (int v = 0; v < 12; ++v)  d0 = fmaf(row[v], q[v], d0);
#pragma unroll
        for (int v = 12; v < 25; ++v) d1 = fmaf(row[v], q[v], d1);
        const float e = __expf((d0 + d1) * (1.f / 25.f));
        den += e;
        const float a = a0v[j];
#pragma unroll
        for (int v = 0; v < 25; ++v) {
            osm[v] = fmaf(e, row[v], osm[v]);
            oa0[v] = fmaf(a, row[v], oa0[v]);
        }
    }

    const float inv = 1.f / den;

    // ---- overlay pack (scalar b32; lane stride 25 dwords, odd -> benign) ----
    {
        float* dst = &sm[t * 25];
#pragma unroll
        for (int v = 0; v < 25; ++v) dst[v] = fmaf(osm[v], inv, oa0[v]);
    }
    __syncthreads();

    // ---- block-contiguous float4 stores: full 64B lines per instruction ----
    {
        float4* og = (float4*)(out + (size_t)nc * TV);
        const float4* sm4 = (const float4*)sm;
#pragma unroll
        for (int i = 0; i < 7; ++i) {
            const int ci = tid + i * 256;
            if (ci < TV / 4) og[ci] = sm4[ci];
        }
    }
}

extern "C" void kernel_launch(void* const* d_in, const int* in_sizes, int n_in,
                              void* d_out, int out_size, void* d_ws, size_t ws_size,
                              hipStream_t stream)
{
    const float* x     = (const float*)d_in[0];
    const float* w     = (const float*)d_in[1];
    const float* cb    = (const float*)d_in[2];
    const float* gamma = (const float*)d_in[3];
    const float* beta  = (const float*)d_in[4];
    const float* rm    = (const float*)d_in[5];
    const float* rv    = (const float*)d_in[6];
    const float* att0  = (const float*)d_in[7];
    float* out = (float*)d_out;
    unsigned short* y = (unsigned short*)d_ws;   // 2048*7168*2 = 29.4 MB padded bf16

    dim3 gA(TV / 128, 16);   // 50 x 16
    conv_mfma<<<gA, 256, 0, stream>>>(x, w, cb, gamma, beta, rm, rv, y);

    dim3 gB(16 * COUT);
    attn_kernel<<<gB, 256, 0, stream>>>(y, att0, out);
}